// Round 7
// baseline (143.797 us; speedup 1.0000x reference)
//
#include <hip/hip_runtime.h>

#define LSEQ 256
#define DMODEL 512
#define NHEAD 8
#define DKH 64
#define BATCH 4

#define TWO_LOG2E 2.885390081777927f

using short8 = __attribute__((ext_vector_type(8))) short;
using f32x4  = __attribute__((ext_vector_type(4))) float;

// split fp32 -> truncated bf16 hi + bf16(lo remainder)
__device__ __forceinline__ void split4(const float* f, ushort4& h, ushort4& l) {
  unsigned short hh[4], ll[4];
#pragma unroll
  for (int j = 0; j < 4; ++j) {
    unsigned int u = __float_as_uint(f[j]);
    hh[j] = (unsigned short)(u >> 16);
    float hf = __uint_as_float(u & 0xFFFF0000u);
    ll[j] = (unsigned short)(__float_as_uint(f[j] - hf) >> 16);
  }
  h = make_ushort4(hh[0], hh[1], hh[2], hh[3]);
  l = make_ushort4(ll[0], ll[1], ll[2], ll[3]);
}

// ---------------------------------------------------------------------------
// prep: z=0..2 -> convert X (q,k,v) to bf16 hi/lo [z][1024][512] (linear)
//       z=3..6 -> convert+transpose W (Wq,Wk,Wv,W0) to [g][n][k] hi/lo
//                 (Wq,Wk prescaled by 2*log2e)
// ---------------------------------------------------------------------------
__global__ __launch_bounds__(256) void prep_kernel(
    const float* __restrict__ q, const float* __restrict__ k, const float* __restrict__ v,
    const float* __restrict__ Wq, const float* __restrict__ Wk,
    const float* __restrict__ Wv, const float* __restrict__ W0,
    unsigned short* __restrict__ xhi, unsigned short* __restrict__ xlo,
    unsigned short* __restrict__ whi, unsigned short* __restrict__ wlo)
{
  const int z = blockIdx.z;
  const int tid = threadIdx.x;
  if (z < 3) {
    const float* X = (z == 0) ? q : (z == 1) ? k : v;
    const int r = blockIdx.x * 32 + (tid >> 3);
    const int c = blockIdx.y * 32 + ((tid & 7) << 2);
    float4 f = *(const float4*)&X[r * DMODEL + c];
    ushort4 h4, l4;
    split4((const float*)&f, h4, l4);
    const int base = (z * 1024 + r) * DMODEL + c;
    *(ushort4*)&xhi[base] = h4;
    *(ushort4*)&xlo[base] = l4;
  } else {
    if (blockIdx.x >= 16) return;
    const int g = z - 3;
    const float* W = (g == 0) ? Wq : (g == 1) ? Wk : (g == 2) ? Wv : W0;
    const float scale = (g < 2) ? TWO_LOG2E : 1.0f;
    const int k0 = blockIdx.x * 32, n0 = blockIdx.y * 32;
    __shared__ float tile[32][36];
    {
      const int r = tid >> 3, c = (tid & 7) << 2;
      float4 f = *(const float4*)&W[(k0 + r) * DMODEL + n0 + c];
      tile[r][c + 0] = f.x * scale;
      tile[r][c + 1] = f.y * scale;
      tile[r][c + 2] = f.z * scale;
      tile[r][c + 3] = f.w * scale;
    }
    __syncthreads();
    const int n = tid >> 3, kk = (tid & 7) << 2;
    float x[4];
#pragma unroll
    for (int j = 0; j < 4; ++j) x[j] = tile[kk + j][n];
    ushort4 h4, l4;
    split4(x, h4, l4);
    const int base = (g * DMODEL + n0 + n) * DMODEL + k0 + kk;
    *(ushort4*)&whi[base] = h4;
    *(ushort4*)&wlo[base] = l4;
  }
}

// ---------------------------------------------------------------------------
// bf16-split MFMA GEMM, BK=32 double-buffered, 32 KB LDS -> 4 blocks/CU.
// Tile 64x64, 4 waves (32x32 quadrant each; 2x2 frags of 16x16x32).
// LDS [buf][Ah,Al,Bh,Bl][slot], slot = row*4 + (chunk ^ (row&3)) of short8;
// staging loads the XOR'd global chunk so both sides use the same involution.
// Per wave-step: 4 global 16B loads, 4 ds_write_b128, 8 ds_read_b128, 12 MFMA.
// 3-product split: hi*hi + hi*lo + lo*hi.
// mode 0: out[R*512+C]; mode 1: qh/vh head layout; mode 2: kT layout
// ---------------------------------------------------------------------------
__device__ __forceinline__ void mfma_gemm(
    const unsigned short* __restrict__ xh, const unsigned short* __restrict__ xl,
    const unsigned short* __restrict__ wh, const unsigned short* __restrict__ wl,
    const float* __restrict__ bias, float bscale,
    float* __restrict__ out, int mode, int bx, int by)
{
  __shared__ short8 lds[2][4][256];   // 32 KB
  const int tid = threadIdx.x;
  const int lane = tid & 63, w = tid >> 6;
  const int bm0 = bx * 64, bn0 = by * 64;

  // staging: thread owns slot tid; row r=tid>>2, chunk c=tid&3 holds
  // global chunk (c ^ (r&3)).
  const int r = tid >> 2, c = tid & 3;
  const int gch = (c ^ (r & 3)) << 3;
  const size_t aoff = (size_t)(bm0 + r) * DMODEL + gch;
  const size_t boff = (size_t)(bn0 + r) * DMODEL + gch;

  const int mrb = (w >> 1) << 5, ncb = (w & 1) << 5;
  const int l15 = lane & 15, lh = lane >> 4;

  // fragment slots (row-major rows, XOR'd chunk): chunk read = lh
  const int ar0 = mrb + l15, ar1 = mrb + 16 + l15;
  const int as0 = ar0 * 4 + (lh ^ (ar0 & 3));
  const int as1 = ar1 * 4 + (lh ^ (ar1 & 3));
  const int br0 = ncb + l15, br1 = ncb + 16 + l15;
  const int bs0 = br0 * 4 + (lh ^ (br0 & 3));
  const int bs1 = br1 * 4 + (lh ^ (br1 & 3));

  short8 sah, sal, sbh, sbl;
#define LOADS(K)                                  \
  { sah = *(const short8*)(xh + aoff + (K));      \
    sal = *(const short8*)(xl + aoff + (K));      \
    sbh = *(const short8*)(wh + boff + (K));      \
    sbl = *(const short8*)(wl + boff + (K)); }
#define WRITES(BUF)                               \
  { lds[BUF][0][tid] = sah; lds[BUF][1][tid] = sal; \
    lds[BUF][2][tid] = sbh; lds[BUF][3][tid] = sbl; }

  f32x4 acc[2][2] = {};
  LOADS(0);
  WRITES(0);
  __syncthreads();

  for (int t = 0; t < 16; ++t) {
    if (t < 15) LOADS((t + 1) * 32);
    const int cur = t & 1;
    short8 a0h = lds[cur][0][as0], a0l = lds[cur][1][as0];
    short8 a1h = lds[cur][0][as1], a1l = lds[cur][1][as1];
    short8 b0h = lds[cur][2][bs0], b0l = lds[cur][3][bs0];
    short8 b1h = lds[cur][2][bs1], b1l = lds[cur][3][bs1];
#define MFMA_(A, B, C) C = __builtin_amdgcn_mfma_f32_16x16x32_bf16(A, B, C, 0, 0, 0)
    MFMA_(a0h, b0h, acc[0][0]); MFMA_(a0h, b0l, acc[0][0]); MFMA_(a0l, b0h, acc[0][0]);
    MFMA_(a0h, b1h, acc[0][1]); MFMA_(a0h, b1l, acc[0][1]); MFMA_(a0l, b1h, acc[0][1]);
    MFMA_(a1h, b0h, acc[1][0]); MFMA_(a1h, b0l, acc[1][0]); MFMA_(a1l, b0h, acc[1][0]);
    MFMA_(a1h, b1h, acc[1][1]); MFMA_(a1h, b1l, acc[1][1]); MFMA_(a1l, b1h, acc[1][1]);
#undef MFMA_
    if (t < 15) WRITES(cur ^ 1);
    __syncthreads();
  }
#undef LOADS
#undef WRITES

  const int bm = bm0 + mrb, bn = bn0 + ncb;
#pragma unroll
  for (int mi = 0; mi < 2; ++mi)
#pragma unroll
    for (int ni = 0; ni < 2; ++ni) {
      const int C = bn + ni * 16 + l15;
      const float bv = bscale * bias[C];
#pragma unroll
      for (int e = 0; e < 4; ++e) {
        const int R = bm + mi * 16 + (lh << 2) + e;
        const float val = acc[mi][ni][e] + bv;
        if (mode == 0) {
          out[R * DMODEL + C] = val;
        } else {
          const int b = R >> 8, l = R & (LSEQ - 1);
          const int hh = C >> 6, dk = C & 63;
          if (mode == 1) out[((b * NHEAD + hh) * LSEQ + l) * DKH + dk] = val;
          else           out[((b * NHEAD + hh) * DKH + dk) * LSEQ + l] = val;
        }
      }
    }
}

__global__ __launch_bounds__(256, 4) void proj_mfma_kernel(
    const unsigned short* __restrict__ xhi, const unsigned short* __restrict__ xlo,
    const unsigned short* __restrict__ whi, const unsigned short* __restrict__ wlo,
    const float* __restrict__ bq, const float* __restrict__ bk, const float* __restrict__ bv,
    float* __restrict__ qh, float* __restrict__ kT, float* __restrict__ vh)
{
  // XCD-bijective swizzle over 384 blocks (=48*8)
  int lin = blockIdx.x + 16 * blockIdx.y + 128 * blockIdx.z;
  lin = (lin & 7) * 48 + (lin >> 3);
  const int bx = lin & 15, by = (lin >> 4) & 7, g = lin >> 7;
  const unsigned short* xh = xhi + (size_t)g * 1024 * DMODEL;
  const unsigned short* xl = xlo + (size_t)g * 1024 * DMODEL;
  const unsigned short* wh = whi + (size_t)g * DMODEL * DMODEL;
  const unsigned short* wl = wlo + (size_t)g * DMODEL * DMODEL;
  if (g == 0)      mfma_gemm(xh, xl, wh, wl, bq, TWO_LOG2E, qh, 1, bx, by);
  else if (g == 1) mfma_gemm(xh, xl, wh, wl, bk, TWO_LOG2E, kT, 2, bx, by);
  else             mfma_gemm(xh, xl, wh, wl, bv, 1.0f, vh, 1, bx, by);
}

__global__ __launch_bounds__(256, 4) void outproj_mfma_kernel(
    const unsigned short* __restrict__ aoh, const unsigned short* __restrict__ aol,
    const unsigned short* __restrict__ whi, const unsigned short* __restrict__ wlo,
    const float* __restrict__ b0, float* __restrict__ out)
{
  int lin = blockIdx.x + 16 * blockIdx.y;     // 128 blocks = 16*8
  lin = (lin & 7) * 16 + (lin >> 3);
  const int bx = lin & 15, by = lin >> 4;
  mfma_gemm(aoh, aol, whi + (size_t)3 * DMODEL * DMODEL,
            wlo + (size_t)3 * DMODEL * DMODEL, b0, 1.0f, out, 0, bx, by);
}

// ---------------------------------------------------------------------------
// Fused Bahdanau attention (unchanged from round 5 except bf16 hi/lo output).
// qh,kT prescaled by 2*log2e. t_j = sum_d vp_d * rcp(exp2(q'+k') + 1);
// softmax in t-space: p = exp2(-2log2e*(t - min t)); masked -> t = +1e9.
// 1024 threads / 16 waves, 2 q-rows per wave; 152 KB LDS, 4 waves/SIMD.
// ---------------------------------------------------------------------------
__global__ __launch_bounds__(1024, 4) void attn_kernel(
    const float* __restrict__ qh,   // (B,H,L,DK) prescaled
    const float* __restrict__ kT,   // (B,H,DK,L) prescaled
    const float* __restrict__ vh,   // (B,H,L,DK)
    const int* __restrict__ mask,   // (B,L,L)
    const float* __restrict__ vp,   // (H,DK)
    unsigned short* __restrict__ aoh,  // (B*L, D) bf16 hi
    unsigned short* __restrict__ aol)  // (B*L, D) bf16 lo
{
  __shared__ float ksh[DKH][LSEQ];      // 64 KB
  __shared__ float vsh[LSEQ][DKH];      // 64 KB
  __shared__ float qsh[32][DKH];        // 8 KB
  __shared__ float psh[16][LSEQ];       // 16 KB
  __shared__ float vpsh[DKH];

  const int bh = blockIdx.x;            // b*8+h
  const int b = bh >> 3, h = bh & 7;
  const int i0 = blockIdx.y * 32;
  const int tid = threadIdx.x;
  const int lane = tid & 63, w = tid >> 6;   // 16 waves

  const float* kbase = kT + (size_t)bh * DKH * LSEQ;
  for (int t = tid; t < DKH * LSEQ / 4; t += 1024) {
    const int d = t >> 6, j4 = (t & 63) << 2;
    *(float4*)&ksh[d][j4] = *(const float4*)&kbase[d * LSEQ + j4];
  }
  const float* vbase = vh + (size_t)bh * LSEQ * DKH;
  for (int t = tid; t < LSEQ * DKH / 4; t += 1024) {
    const int j = t >> 4, d4 = (t & 15) << 2;
    *(float4*)&vsh[j][d4] = *(const float4*)&vbase[j * DKH + d4];
  }
  if (tid < 512) {
    const float* qbase = qh + ((size_t)bh * LSEQ + i0) * DKH;
    const int r = tid >> 4, d4 = (tid & 15) << 2;
    *(float4*)&qsh[r][d4] = *(const float4*)&qbase[r * DKH + d4];
  }
  if (tid < DKH) vpsh[tid] = vp[h * DKH + tid];
  __syncthreads();

  // ---- score phase: 2 rows per wave. tj[r][c]: rows w*2+r, cols c*64+lane
  float tj[2][4] = {};
#pragma unroll 2
  for (int g = 0; g < 16; ++g) {
    float kv[16];     // [t][c]
#pragma unroll
    for (int t = 0; t < 4; ++t)
#pragma unroll
      for (int c = 0; c < 4; ++c)
        kv[t * 4 + c] = ksh[(g << 2) + t][(c << 6) + lane];
    float vpv[4];
    *(float4*)vpv = *(const float4*)&vpsh[g << 2];
#pragma unroll
    for (int r = 0; r < 2; ++r) {
      float q_[4];
      *(float4*)q_ = *(const float4*)&qsh[(w << 1) + r][g << 2];
#pragma unroll
      for (int t = 0; t < 4; ++t)
#pragma unroll
        for (int c = 0; c < 4; ++c) {
          const float x = q_[t] + kv[t * 4 + c];
          const float e = __builtin_amdgcn_exp2f(x);
          tj[r][c] = fmaf(vpv[t], __builtin_amdgcn_rcpf(e + 1.f), tj[r][c]);
        }
    }
  }

  // ---- per-row: mask, softmax (t-space), PV ----
  const int cg = lane >> 4, qq = lane & 15;
#pragma unroll
  for (int r = 0; r < 2; ++r) {
    const int i = i0 + (w << 1) + r;
    const int* mrow = mask + ((size_t)b * LSEQ + i) * LSEQ;
    float t4[4];
#pragma unroll
    for (int c = 0; c < 4; ++c) {
      const int mv = mrow[(c << 6) + lane];
      t4[c] = mv ? tj[r][c] : 1.0e9f;
    }
    float m = fminf(fminf(t4[0], t4[1]), fminf(t4[2], t4[3]));
#pragma unroll
    for (int off = 32; off; off >>= 1) m = fminf(m, __shfl_xor(m, off));
    const float m2 = m * TWO_LOG2E;
    float p[4];
    float sum = 0.f;
#pragma unroll
    for (int c = 0; c < 4; ++c) {
      p[c] = __builtin_amdgcn_exp2f(fmaf(t4[c], -TWO_LOG2E, m2));
      sum += p[c];
    }
#pragma unroll
    for (int off = 32; off; off >>= 1) sum += __shfl_xor(sum, off);
    const float rs = __builtin_amdgcn_rcpf(sum);
#pragma unroll
    for (int c = 0; c < 4; ++c) psh[w][(c << 6) + lane] = p[c];

    float o[4] = {0.f, 0.f, 0.f, 0.f};
#pragma unroll 4
    for (int jg = 0; jg < 16; ++jg) {
      float pv[4];
      *(float4*)pv = *(const float4*)&psh[w][(cg << 6) + (jg << 2)];
#pragma unroll
      for (int t = 0; t < 4; ++t) {
        float v_[4];
        *(float4*)v_ = *(const float4*)&vsh[(cg << 6) + (jg << 2) + t][qq << 2];
#pragma unroll
        for (int u = 0; u < 4; ++u) o[u] = fmaf(pv[t], v_[u], o[u]);
      }
    }
#pragma unroll
    for (int off = 16; off <= 32; off <<= 1) {
#pragma unroll
      for (int u = 0; u < 4; ++u) o[u] += __shfl_xor(o[u], off);
    }
    if (lane < 16) {
      float ov[4];
#pragma unroll
      for (int u = 0; u < 4; ++u) ov[u] = o[u] * rs;
      ushort4 h4, l4;
      split4(ov, h4, l4);
      const int base = ((size_t)b * LSEQ + i) * DMODEL + h * DKH + (qq << 2);
      *(ushort4*)&aoh[base] = h4;
      *(ushort4*)&aol[base] = l4;
    }
  }
}

// ---------------------------------------------------------------------------
extern "C" void kernel_launch(void* const* d_in, const int* in_sizes, int n_in,
                              void* d_out, int out_size, void* d_ws, size_t ws_size,
                              hipStream_t stream) {
  const float* q   = (const float*)d_in[0];
  const float* k   = (const float*)d_in[1];
  const float* v   = (const float*)d_in[2];
  const int*  mask = (const int*)d_in[3];
  const float* Wq  = (const float*)d_in[4];
  const float* bq  = (const float*)d_in[5];
  const float* Wk  = (const float*)d_in[6];
  const float* bk  = (const float*)d_in[7];
  const float* Wv  = (const float*)d_in[8];
  const float* bv  = (const float*)d_in[9];
  const float* vp  = (const float*)d_in[10];
  const float* W0  = (const float*)d_in[11];
  const float* b0  = (const float*)d_in[12];
  float* outp = (float*)d_out;

  char* wsb = (char*)d_ws;
  unsigned short* whi = (unsigned short*)(wsb);               // 2 MB
  unsigned short* wlo = (unsigned short*)(wsb + (2u << 20));  // 2 MB
  unsigned short* xhi = (unsigned short*)(wsb + (4u << 20));  // 3 MB
  unsigned short* xlo = (unsigned short*)(wsb + (7u << 20));  // 3 MB
  float* qh = (float*)(wsb + (10u << 20));                    // 2 MB
  float* kT = (float*)(wsb + (12u << 20));                    // 2 MB
  float* vh = (float*)(wsb + (14u << 20));                    // 2 MB
  unsigned short* aoh = xhi;   // overlay: x(q,k,v) dead after proj
  unsigned short* aol = xlo;

  prep_kernel<<<dim3(32, 16, 7), 256, 0, stream>>>(q, k, v, Wq, Wk, Wv, W0,
                                                   xhi, xlo, whi, wlo);
  proj_mfma_kernel<<<dim3(16, 8, 3), 256, 0, stream>>>(xhi, xlo, whi, wlo,
                                                       bq, bk, bv, qh, kT, vh);
  attn_kernel<<<dim3(32, 8), 1024, 0, stream>>>(qh, kT, vh, mask, vp, aoh, aol);
  outproj_mfma_kernel<<<dim3(16, 8), 256, 0, stream>>>(aoh, aol, whi, wlo, b0, outp);
}